// Round 11
// baseline (99.753 us; speedup 1.0000x reference)
//
#include <hip/hip_runtime.h>
#include <float.h>
#include <math.h>

#define T_DIM 2048
#define C_DIM 512
#define QKV_LD 1536
#define NBLK 512

typedef float f32x4 __attribute__((ext_vector_type(4)));
typedef short s16x8 __attribute__((ext_vector_type(8)));

__device__ __forceinline__ unsigned short f2bf(float f) {
  unsigned u = __float_as_uint(f);
  return (unsigned short)((u + 0x7fffu + ((u >> 16) & 1u)) >> 16);
}

// async 16B global->LDS; LDS dest must be wave-uniform base + lane*16.
__device__ __forceinline__ void load16_to_lds(const void* g, void* l) {
  __builtin_amdgcn_global_load_lds(
      (const __attribute__((address_space(1))) unsigned int*)g,
      (__attribute__((address_space(3))) unsigned int*)(unsigned int)(unsigned long long)l,
      16, 0, 0);
}

// ---------------------------------------------------------------------------
// Resident-B prologue: transpose+cast a 64-col fp32 W panel into LDS.
// lB[n][k] rows of 512 bf16; 16B chunk slot XOR-swizzled: slot = chunk^(n&7).
// Wave-coalesced reads (64 consecutive n per k-row); b128 writes at bank floor.
// ---------------------------------------------------------------------------
__device__ __forceinline__ void stage_B_panel(const float* __restrict__ W, int ldw,
                                              int n0, unsigned short* lB,
                                              int lane, int w) {
  const int n = n0 + lane;
#pragma unroll
  for (int ko = 0; ko < 16; ++ko) {
    const int chunk = ko * 4 + w;      // 0..63 -> k = chunk*8 .. +7
    const int kbase = chunk * 8;
    float f[8];
#pragma unroll
    for (int j = 0; j < 8; ++j)
      f[j] = W[(size_t)(kbase + j) * ldw + n];
    uint4 o;
    o.x = f2bf(f[0]) | ((unsigned)f2bf(f[1]) << 16);
    o.y = f2bf(f[2]) | ((unsigned)f2bf(f[3]) << 16);
    o.z = f2bf(f[4]) | ((unsigned)f2bf(f[5]) << 16);
    o.w = f2bf(f[6]) | ((unsigned)f2bf(f[7]) << 16);
    const int slot = chunk ^ (lane & 7);
    *(uint4*)(lB + lane * 512 + slot * 8) = o;
  }
}

// ---------------------------------------------------------------------------
// gemm1: qkvbf[2048][1536] = bf16( x[2048][512] @ Wqkv[512][1536] ).
// 384 blocks of 128x64.  B resident in LDS (64 KB, once/block); A ingested
// fp32 -> bf16 with next-iter prefetch overlapping the MFMA phase.
// ---------------------------------------------------------------------------
__global__ __launch_bounds__(256) void gemm1_kernel(const float* __restrict__ x,
                                                    const float* __restrict__ Wqkv,
                                                    unsigned short* __restrict__ qkvbf) {
  __shared__ __align__(16) unsigned short lB[64 * 512];   // 64 KB resident
  __shared__ __align__(16) unsigned short lA[128 * 32];   // 8 KB staged/iter
  const int tid = threadIdx.x, bid = blockIdx.x;
  const int lane = tid & 63, w = tid >> 6, wr = w >> 1, wc = w & 1;
  const int fm = lane & 15, q4 = lane >> 4, q8 = q4 * 8;
  const int m0 = (bid / 24) * 128, n0 = (bid % 24) * 64;

  stage_B_panel(Wqkv, QKV_LD, n0, lB, lane, w);

  const int a_row = tid >> 2, a_c8 = (tid & 3) * 8;   // chunk c = tid (+256)
  const int a_row2 = a_row + 64;
  float4 g[4];
  auto loadA = [&](int kk) {
    const float* s0 = &x[(size_t)(m0 + a_row) * C_DIM + kk + a_c8];
    const float* s1 = &x[(size_t)(m0 + a_row2) * C_DIM + kk + a_c8];
    g[0] = *(const float4*)s0; g[1] = *(const float4*)(s0 + 4);
    g[2] = *(const float4*)s1; g[3] = *(const float4*)(s1 + 4);
  };
  loadA(0);

  f32x4 acc[4][2] = {};
  for (int i = 0; i < 16; ++i) {
    __syncthreads();                       // lA reuse (covers B prologue at i=0)
#pragma unroll
    for (int ii = 0; ii < 2; ++ii) {
      float4 v0 = g[ii * 2], v1 = g[ii * 2 + 1];
      uint4 o;
      o.x = f2bf(v0.x) | ((unsigned)f2bf(v0.y) << 16);
      o.y = f2bf(v0.z) | ((unsigned)f2bf(v0.w) << 16);
      o.z = f2bf(v1.x) | ((unsigned)f2bf(v1.y) << 16);
      o.w = f2bf(v1.z) | ((unsigned)f2bf(v1.w) << 16);
      *(uint4*)(lA + (ii ? a_row2 : a_row) * 32 + a_c8) = o;
    }
    __syncthreads();
    if (i < 15) loadA((i + 1) * 32);       // prefetch overlaps MFMA phase

    s16x8 a[4], b[2];
#pragma unroll
    for (int mi = 0; mi < 4; ++mi)
      a[mi] = *(const s16x8*)&lA[(wr * 64 + mi * 16 + fm) * 32 + q8];
#pragma unroll
    for (int ni = 0; ni < 2; ++ni) {
      int n = wc * 32 + ni * 16 + fm;
      int slot = (i * 4 + q4) ^ (n & 7);
      b[ni] = *(const s16x8*)&lB[n * 512 + slot * 8];
    }
#pragma unroll
    for (int mi = 0; mi < 4; ++mi)
#pragma unroll
      for (int ni = 0; ni < 2; ++ni)
        acc[mi][ni] = __builtin_amdgcn_mfma_f32_16x16x32_bf16(a[mi], b[ni], acc[mi][ni], 0, 0, 0);
  }
#pragma unroll
  for (int mi = 0; mi < 4; ++mi)
#pragma unroll
    for (int ni = 0; ni < 2; ++ni)
#pragma unroll
      for (int r = 0; r < 4; ++r) {
        int row = m0 + wr * 64 + mi * 16 + q4 * 4 + r;
        int col = n0 + wc * 32 + ni * 16 + fm;
        qkvbf[(size_t)row * QKV_LD + col] = f2bf(acc[mi][ni][r]);
      }
}

// ---------------------------------------------------------------------------
// gemm2: out[2048][512] = fp32( Ybf[2048][512] @ Wout[512][512] ).
// 256 blocks of 64x64.  B resident (64 KB); A bf16 via global_load_lds.
// ---------------------------------------------------------------------------
__global__ __launch_bounds__(256) void gemm2_kernel(const unsigned short* __restrict__ Ybf,
                                                    const float* __restrict__ Wout,
                                                    float* __restrict__ out) {
  __shared__ __align__(16) unsigned short lB[64 * 512];   // 64 KB resident
  __shared__ __align__(16) unsigned short lA[64 * 32];    // 4 KB staged/iter
  const int tid = threadIdx.x, bid = blockIdx.x;
  const int lane = tid & 63, w = tid >> 6, wr = w >> 1, wc = w & 1;
  const int fm = lane & 15, q4 = lane >> 4, q8 = q4 * 8;
  const int m0 = (bid / 8) * 64, n0 = (bid % 8) * 64;

  stage_B_panel(Wout, C_DIM, n0, lB, lane, w);

  const int a_row = tid >> 2, a_c8 = (tid & 3) * 8;  // one 16B chunk per thread
  f32x4 acc[2][2] = {};
  for (int i = 0; i < 16; ++i) {
    __syncthreads();
    load16_to_lds(&Ybf[(size_t)(m0 + a_row) * C_DIM + i * 32 + a_c8], lA + tid * 8);
    __syncthreads();

    s16x8 a[2], b[2];
#pragma unroll
    for (int mi = 0; mi < 2; ++mi)
      a[mi] = *(const s16x8*)&lA[(wr * 32 + mi * 16 + fm) * 32 + q8];
#pragma unroll
    for (int ni = 0; ni < 2; ++ni) {
      int n = wc * 32 + ni * 16 + fm;
      int slot = (i * 4 + q4) ^ (n & 7);
      b[ni] = *(const s16x8*)&lB[n * 512 + slot * 8];
    }
#pragma unroll
    for (int mi = 0; mi < 2; ++mi)
#pragma unroll
      for (int ni = 0; ni < 2; ++ni)
        acc[mi][ni] = __builtin_amdgcn_mfma_f32_16x16x32_bf16(a[mi], b[ni], acc[mi][ni], 0, 0, 0);
  }
#pragma unroll
  for (int mi = 0; mi < 2; ++mi)
#pragma unroll
    for (int ni = 0; ni < 2; ++ni)
#pragma unroll
      for (int r = 0; r < 4; ++r) {
        int row = m0 + wr * 32 + mi * 16 + q4 * 4 + r;
        int col = n0 + wc * 32 + ni * 16 + fm;
        out[(size_t)row * C_DIM + col] = acc[mi][ni][r];
      }
}

// ---------------------------------------------------------------------------
// MFMA attention: 512 blocks (8 heads x 64 t-tiles of 32 slots). (R10 best)
// ---------------------------------------------------------------------------
__global__ __launch_bounds__(256) void attn_kernel(const unsigned short* __restrict__ qkvbf,
                                                   const int* __restrict__ perms,
                                                   unsigned short* __restrict__ Ybf) {
  __shared__ __align__(16) unsigned char smem[48768];
  int* ow            = (int*)smem;                           // [128]
  unsigned short* lQ = (unsigned short*)(smem + 512);        // [32][72]
  unsigned short* lK = (unsigned short*)(smem + 5120);       // [128][72]
  float* Sb          = (float*)(smem + 23552);               // [32][129]
  unsigned short* lP = (unsigned short*)(smem + 40064);      // [32][136]
  unsigned short* lVT= (unsigned short*)(smem + 5120);       // [64][136] overlays lK

  const int tid = threadIdx.x, bid = blockIdx.x;
  const int lane = tid & 63, w = tid >> 6;
  const int fm = lane & 15, q8 = (lane >> 4) * 8, q4 = lane >> 4;
  const int h = bid >> 6;
  const int t0 = (bid & 63) << 5;

  if (tid < 128) {
    int pi = t0 - 48 + tid;
    int idx = min(max(pi, 0), T_DIM - 1);
    ow[tid] = perms[h * T_DIM + idx];
  }
  __syncthreads();

#pragma unroll
  for (int it = 0; it < 4; ++it) {
    int c = it * 256 + tid;
    int row = c >> 3, k8 = c & 7;
    uint4 d = *(const uint4*)(qkvbf + (size_t)ow[row] * QKV_LD + C_DIM + h * 64 + k8 * 8);
    *(uint4*)(lK + row * 72 + k8 * 8) = d;
  }
  {
    int row = tid >> 3, k8 = tid & 7;
    uint4 d = *(const uint4*)(qkvbf + (size_t)ow[48 + row] * QKV_LD + h * 64 + k8 * 8);
    *(uint4*)(lQ + row * 72 + k8 * 8) = d;
  }
  __syncthreads();

  // S = Q·K^T via MFMA; wave w owns key-cols [w*32, w*32+32)
  {
    f32x4 accs[2][2] = {};
#pragma unroll
    for (int kt = 0; kt < 2; ++kt) {
      s16x8 aq[2];
#pragma unroll
      for (int mi = 0; mi < 2; ++mi)
        aq[mi] = *(const s16x8*)&lQ[(mi * 16 + fm) * 72 + kt * 32 + q8];
#pragma unroll
      for (int ni = 0; ni < 2; ++ni) {
        s16x8 bk = *(const s16x8*)&lK[(w * 32 + ni * 16 + fm) * 72 + kt * 32 + q8];
#pragma unroll
        for (int mi = 0; mi < 2; ++mi)
          accs[mi][ni] = __builtin_amdgcn_mfma_f32_16x16x32_bf16(aq[mi], bk, accs[mi][ni], 0, 0, 0);
      }
    }
#pragma unroll
    for (int mi = 0; mi < 2; ++mi)
#pragma unroll
      for (int ni = 0; ni < 2; ++ni)
#pragma unroll
        for (int r = 0; r < 4; ++r)
          Sb[(mi * 16 + q4 * 4 + r) * 129 + w * 32 + ni * 16 + fm] = accs[mi][ni][r] * 0.125f;
  }
  __syncthreads();

  // stage V^T [64 d][128 key] over lK; lanes span row-pairs -> conflict-free
#pragma unroll
  for (int it = 0; it < 2; ++it) {
    int c2 = it * 256 + tid;
    int r = c2 & 63, d0 = (c2 >> 6) * 8;
    uint4 va = *(const uint4*)(qkvbf + (size_t)ow[2 * r]     * QKV_LD + 2 * C_DIM + h * 64 + d0);
    uint4 vb = *(const uint4*)(qkvbf + (size_t)ow[2 * r + 1] * QKV_LD + 2 * C_DIM + h * 64 + d0);
    *(unsigned*)(lVT + (d0 + 0) * 136 + 2 * r) = (va.x & 0xffffu) | (vb.x << 16);
    *(unsigned*)(lVT + (d0 + 1) * 136 + 2 * r) = (va.x >> 16) | (vb.x & 0xffff0000u);
    *(unsigned*)(lVT + (d0 + 2) * 136 + 2 * r) = (va.y & 0xffffu) | (vb.y << 16);
    *(unsigned*)(lVT + (d0 + 3) * 136 + 2 * r) = (va.y >> 16) | (vb.y & 0xffff0000u);
    *(unsigned*)(lVT + (d0 + 4) * 136 + 2 * r) = (va.z & 0xffffu) | (vb.z << 16);
    *(unsigned*)(lVT + (d0 + 5) * 136 + 2 * r) = (va.z >> 16) | (vb.z & 0xffff0000u);
    *(unsigned*)(lVT + (d0 + 6) * 136 + 2 * r) = (va.w & 0xffffu) | (vb.w << 16);
    *(unsigned*)(lVT + (d0 + 7) * 136 + 2 * r) = (va.w >> 16) | (vb.w & 0xffff0000u);
  }

  // softmax: wave w owns q-rows w*8..w*8+7; lane owns cols (lane, lane+64)
  for (int si = 0; si < 8; ++si) {
    const int s = w * 8 + si;
    const int p = ow[48 + s];
    const int c1 = lane + 64;
    const float v0 = Sb[s * 129 + lane];
    const float v1 = Sb[s * 129 + c1];
    const int pi0 = t0 - 48 + lane;
    const bool valid0 = (lane >= s) && (pi0 >= 0) && (pi0 < T_DIM) && (ow[lane] <= p);
    const bool valid1 = (lane <= s + 32) && (pi0 + 64 < T_DIM) && (ow[c1] <= p);
    float mx = fmaxf(valid0 ? v0 : -FLT_MAX, valid1 ? v1 : -FLT_MAX);
#pragma unroll
    for (int off = 32; off > 0; off >>= 1) mx = fmaxf(mx, __shfl_xor(mx, off, 64));
    const float e0 = valid0 ? __expf(v0 - mx) : 0.f;
    const float e1 = valid1 ? __expf(v1 - mx) : 0.f;
    float sum = e0 + e1;
#pragma unroll
    for (int off = 32; off > 0; off >>= 1) sum += __shfl_xor(sum, off, 64);
    const float inv = 1.f / sum;
    lP[s * 136 + lane] = valid0 ? f2bf(e0 * inv) : (unsigned short)0;
    lP[s * 136 + c1]   = valid1 ? f2bf(e1 * inv) : (unsigned short)0;
  }
  __syncthreads();

  // O = P·V^T via MFMA; wave (wr,wc): m-tile wr, n-tiles wc*2+{0,1}
  {
    const int wr = w >> 1, wc = w & 1;
    f32x4 acco[2] = {};
#pragma unroll
    for (int kt = 0; kt < 4; ++kt) {
      s16x8 ap = *(const s16x8*)&lP[(wr * 16 + fm) * 136 + kt * 32 + q8];
#pragma unroll
      for (int ni = 0; ni < 2; ++ni) {
        s16x8 bv = *(const s16x8*)&lVT[((wc * 2 + ni) * 16 + fm) * 136 + kt * 32 + q8];
        acco[ni] = __builtin_amdgcn_mfma_f32_16x16x32_bf16(ap, bv, acco[ni], 0, 0, 0);
      }
    }
#pragma unroll
    for (int ni = 0; ni < 2; ++ni)
#pragma unroll
      for (int r = 0; r < 4; ++r) {
        int q = wr * 16 + q4 * 4 + r;
        int d = (wc * 2 + ni) * 16 + fm;
        Ybf[(size_t)ow[48 + q] * C_DIM + h * 64 + d] = f2bf(acco[ni][r]);
      }
  }
}

// ---------------------------------------------------------------------------
extern "C" void kernel_launch(void* const* d_in, const int* in_sizes, int n_in,
                              void* d_out, int out_size, void* d_ws, size_t ws_size,
                              hipStream_t stream) {
  const float* x     = (const float*)d_in[0];
  const float* Wqkv  = (const float*)d_in[1];
  const float* Wout  = (const float*)d_in[2];
  const int*   perms = (const int*)d_in[3];
  float* out = (float*)d_out;
  unsigned short* ws = (unsigned short*)d_ws;

  unsigned short* qkvbf = ws;                    // [2048][1536] bf16
  unsigned short* Ybf   = qkvbf + 3145728;       // [2048][512]  bf16

  gemm1_kernel<<<384, 256, 0, stream>>>(x, Wqkv, qkvbf);
  attn_kernel<<<NBLK, 256, 0, stream>>>(qkvbf, perms, Ybf);
  gemm2_kernel<<<256, 256, 0, stream>>>(Ybf, Wout, out);
}

// Round 12
// 95.536 us; speedup vs baseline: 1.0441x; 1.0441x over previous
//
#include <hip/hip_runtime.h>
#include <float.h>
#include <math.h>

#define T_DIM 2048
#define C_DIM 512
#define QKV_LD 1536
#define NBLK 512

typedef float f32x4 __attribute__((ext_vector_type(4)));
typedef short s16x8 __attribute__((ext_vector_type(8)));

__device__ __forceinline__ unsigned short f2bf(float f) {
  unsigned u = __float_as_uint(f);
  return (unsigned short)((u + 0x7fffu + ((u >> 16) & 1u)) >> 16);
}

// async 16B global->LDS; LDS dest must be wave-uniform base + lane*16.
__device__ __forceinline__ void load16_to_lds(const void* g, void* l) {
  __builtin_amdgcn_global_load_lds(
      (const __attribute__((address_space(1))) unsigned int*)g,
      (__attribute__((address_space(3))) unsigned int*)(unsigned int)(unsigned long long)l,
      16, 0, 0);
}

// ---------------------------------------------------------------------------
// prep: cast x -> bf16; transpose+cast Wqkv, Wout.  512 blocks.
// NOTE (R7/R11 lesson): shared-operand conversion must happen ONCE here;
// folding it into the GEMMs (per-block, 16-24x redundant) regressed twice.
// ---------------------------------------------------------------------------
__global__ __launch_bounds__(256) void prep_kernel(const float* __restrict__ x,
                                                   const float* __restrict__ Wqkv,
                                                   const float* __restrict__ Wout,
                                                   unsigned short* __restrict__ xbf,
                                                   unsigned short* __restrict__ WqkvT,
                                                   unsigned short* __restrict__ WoutT) {
  __shared__ float tile[32][33];
  const int tid = threadIdx.x, bid = blockIdx.x;

  const float4* xs4 = (const float4*)x;
  for (int i = bid * 256 + tid; i < (T_DIM * C_DIM) / 4; i += NBLK * 256) {
    float4 v = xs4[i];
    ushort4 o;
    o.x = f2bf(v.x); o.y = f2bf(v.y); o.z = f2bf(v.z); o.w = f2bf(v.w);
    ((ushort4*)xbf)[i] = o;
  }
  const int tx = tid & 31, ty = tid >> 5;
  for (int tt = bid; tt < 1024; tt += NBLK) {
    const float* src; unsigned short* dst; int Cc, R, bx, by;
    if (tt < 768) { src = Wqkv; dst = WqkvT; Cc = QKV_LD; R = C_DIM; bx = (tt % 48) * 32; by = (tt / 48) * 32; }
    else { int u = tt - 768; src = Wout; dst = WoutT; Cc = C_DIM; R = C_DIM; bx = (u & 15) * 32; by = (u >> 4) * 32; }
    __syncthreads();
#pragma unroll
    for (int i = 0; i < 4; ++i) { int r = ty + i * 8; tile[r][tx] = src[(size_t)(by + r) * Cc + bx + tx]; }
    __syncthreads();
#pragma unroll
    for (int i = 0; i < 4; ++i) { int r = ty + i * 8; dst[(size_t)(bx + r) * R + by + tx] = f2bf(tile[tx][r]); }
  }
}

// ---------------------------------------------------------------------------
// bf16 MFMA GEMM: C = A[M,K] * BT[N,K]^T.  One tile per block, BK=32 (best
// measured; BK=64 / BN=96 / fused-ingest variants all neutral or worse).
// ---------------------------------------------------------------------------
template <int BM, int BN, bool OUT16>
__device__ __forceinline__ void gemm_body(const unsigned short* __restrict__ A,
                                          const unsigned short* __restrict__ BT,
                                          void* __restrict__ Cp,
                                          int N, int K, int tilesX,
                                          unsigned short* lA, unsigned short* lB,
                                          int tid, int bid) {
  constexpr int BK = 32;
  constexpr int BM2 = BM / 2, BN2 = BN / 2;
  constexpr int MT = BM2 / 16, NT = BN2 / 16;
  constexpr int IA = BM / 64;
  constexpr int IB = BN / 64;
  const int lane = tid & 63, w = tid >> 6, wr = w >> 1, wc = w & 1;
  const int fm = lane & 15, q8 = (lane >> 4) * 8, q4 = lane >> 4;

  const int m0 = (bid / tilesX) * BM, n0 = (bid % tilesX) * BN;
  f32x4 acc[MT][NT] = {};
  for (int k0 = 0; k0 < K; k0 += BK) {
    __syncthreads();
#pragma unroll
    for (int i = 0; i < IA; ++i) {
      int c = i * 256 + tid, row = c >> 2, c8 = (c & 3) * 8;
      load16_to_lds(&A[(size_t)(m0 + row) * K + k0 + c8], lA + c * 8);
    }
#pragma unroll
    for (int i = 0; i < IB; ++i) {
      int c = i * 256 + tid, row = c >> 2, c8 = (c & 3) * 8;
      load16_to_lds(&BT[(size_t)(n0 + row) * K + k0 + c8], lB + c * 8);
    }
    __syncthreads();
    s16x8 a[MT], b[NT];
#pragma unroll
    for (int mi = 0; mi < MT; ++mi)
      a[mi] = *(const s16x8*)&lA[(wr * BM2 + mi * 16 + fm) * BK + q8];
#pragma unroll
    for (int ni = 0; ni < NT; ++ni)
      b[ni] = *(const s16x8*)&lB[(wc * BN2 + ni * 16 + fm) * BK + q8];
#pragma unroll
    for (int mi = 0; mi < MT; ++mi)
#pragma unroll
      for (int ni = 0; ni < NT; ++ni)
        acc[mi][ni] = __builtin_amdgcn_mfma_f32_16x16x32_bf16(a[mi], b[ni], acc[mi][ni], 0, 0, 0);
  }
#pragma unroll
  for (int mi = 0; mi < MT; ++mi)
#pragma unroll
    for (int ni = 0; ni < NT; ++ni)
#pragma unroll
      for (int r = 0; r < 4; ++r) {
        int row = m0 + wr * BM2 + mi * 16 + q4 * 4 + r;
        int col = n0 + wc * BN2 + ni * 16 + fm;
        if constexpr (OUT16)
          ((unsigned short*)Cp)[(size_t)row * N + col] = f2bf(acc[mi][ni][r]);
        else
          ((float*)Cp)[(size_t)row * N + col] = acc[mi][ni][r];
      }
}

__global__ __launch_bounds__(256) void gemm1_kernel(const unsigned short* __restrict__ A,
                                                    const unsigned short* __restrict__ BT,
                                                    unsigned short* __restrict__ Cc) {
  __shared__ __align__(16) unsigned short smem[(128 + 64) * 32];
  gemm_body<128, 64, true>(A, BT, Cc, QKV_LD, C_DIM, 24, smem, smem + 128 * 32,
                           threadIdx.x, blockIdx.x);
}
__global__ __launch_bounds__(256) void gemm2_kernel(const unsigned short* __restrict__ A,
                                                    const unsigned short* __restrict__ BT,
                                                    float* __restrict__ Cc) {
  __shared__ __align__(16) unsigned short smem[(64 + 64) * 32];
  gemm_body<64, 64, false>(A, BT, Cc, C_DIM, C_DIM, 8, smem, smem + 64 * 32,
                           threadIdx.x, blockIdx.x);
}

// ---------------------------------------------------------------------------
// MFMA attention: 512 blocks (8 heads x 64 t-tiles of 32 slots).
// V^T staging: lanes span row-pairs -> conflict-free LDS banks (R10 fix,
// measured -2.5 us vs dim-spanning layout).
// ---------------------------------------------------------------------------
__global__ __launch_bounds__(256) void attn_kernel(const unsigned short* __restrict__ qkvbf,
                                                   const int* __restrict__ perms,
                                                   unsigned short* __restrict__ Ybf) {
  __shared__ __align__(16) unsigned char smem[48768];
  int* ow            = (int*)smem;                           // [128]
  unsigned short* lQ = (unsigned short*)(smem + 512);        // [32][72]
  unsigned short* lK = (unsigned short*)(smem + 5120);       // [128][72]
  float* Sb          = (float*)(smem + 23552);               // [32][129]
  unsigned short* lP = (unsigned short*)(smem + 40064);      // [32][136]
  unsigned short* lVT= (unsigned short*)(smem + 5120);       // [64][136] overlays lK

  const int tid = threadIdx.x, bid = blockIdx.x;
  const int lane = tid & 63, w = tid >> 6;
  const int fm = lane & 15, q8 = (lane >> 4) * 8, q4 = lane >> 4;
  const int h = bid >> 6;
  const int t0 = (bid & 63) << 5;

  if (tid < 128) {
    int pi = t0 - 48 + tid;
    int idx = min(max(pi, 0), T_DIM - 1);
    ow[tid] = perms[h * T_DIM + idx];
  }
  __syncthreads();

#pragma unroll
  for (int it = 0; it < 4; ++it) {
    int c = it * 256 + tid;
    int row = c >> 3, k8 = c & 7;
    uint4 d = *(const uint4*)(qkvbf + (size_t)ow[row] * QKV_LD + C_DIM + h * 64 + k8 * 8);
    *(uint4*)(lK + row * 72 + k8 * 8) = d;
  }
  {
    int row = tid >> 3, k8 = tid & 7;
    uint4 d = *(const uint4*)(qkvbf + (size_t)ow[48 + row] * QKV_LD + h * 64 + k8 * 8);
    *(uint4*)(lQ + row * 72 + k8 * 8) = d;
  }
  __syncthreads();

  // S = Q·K^T via MFMA; wave w owns key-cols [w*32, w*32+32)
  {
    f32x4 accs[2][2] = {};
#pragma unroll
    for (int kt = 0; kt < 2; ++kt) {
      s16x8 aq[2];
#pragma unroll
      for (int mi = 0; mi < 2; ++mi)
        aq[mi] = *(const s16x8*)&lQ[(mi * 16 + fm) * 72 + kt * 32 + q8];
#pragma unroll
      for (int ni = 0; ni < 2; ++ni) {
        s16x8 bk = *(const s16x8*)&lK[(w * 32 + ni * 16 + fm) * 72 + kt * 32 + q8];
#pragma unroll
        for (int mi = 0; mi < 2; ++mi)
          accs[mi][ni] = __builtin_amdgcn_mfma_f32_16x16x32_bf16(aq[mi], bk, accs[mi][ni], 0, 0, 0);
      }
    }
#pragma unroll
    for (int mi = 0; mi < 2; ++mi)
#pragma unroll
      for (int ni = 0; ni < 2; ++ni)
#pragma unroll
        for (int r = 0; r < 4; ++r)
          Sb[(mi * 16 + q4 * 4 + r) * 129 + w * 32 + ni * 16 + fm] = accs[mi][ni][r] * 0.125f;
  }
  __syncthreads();

  // stage V^T [64 d][128 key] over lK.  Work item c2: row-pair r = c2&63,
  // dim-chunk d0 = (c2>>6)*8.  Consecutive lanes -> consecutive r ->
  // addr/4 = (d0+i)*68 + r -> conflict-free banks.  b32 packs rows 2r,2r+1.
#pragma unroll
  for (int it = 0; it < 2; ++it) {
    int c2 = it * 256 + tid;
    int r = c2 & 63, d0 = (c2 >> 6) * 8;
    uint4 va = *(const uint4*)(qkvbf + (size_t)ow[2 * r]     * QKV_LD + 2 * C_DIM + h * 64 + d0);
    uint4 vb = *(const uint4*)(qkvbf + (size_t)ow[2 * r + 1] * QKV_LD + 2 * C_DIM + h * 64 + d0);
    *(unsigned*)(lVT + (d0 + 0) * 136 + 2 * r) = (va.x & 0xffffu) | (vb.x << 16);
    *(unsigned*)(lVT + (d0 + 1) * 136 + 2 * r) = (va.x >> 16) | (vb.x & 0xffff0000u);
    *(unsigned*)(lVT + (d0 + 2) * 136 + 2 * r) = (va.y & 0xffffu) | (vb.y << 16);
    *(unsigned*)(lVT + (d0 + 3) * 136 + 2 * r) = (va.y >> 16) | (vb.y & 0xffff0000u);
    *(unsigned*)(lVT + (d0 + 4) * 136 + 2 * r) = (va.z & 0xffffu) | (vb.z << 16);
    *(unsigned*)(lVT + (d0 + 5) * 136 + 2 * r) = (va.z >> 16) | (vb.z & 0xffff0000u);
    *(unsigned*)(lVT + (d0 + 6) * 136 + 2 * r) = (va.w & 0xffffu) | (vb.w << 16);
    *(unsigned*)(lVT + (d0 + 7) * 136 + 2 * r) = (va.w >> 16) | (vb.w & 0xffff0000u);
  }

  // softmax: wave w owns q-rows w*8..w*8+7; lane owns cols (lane, lane+64)
  for (int si = 0; si < 8; ++si) {
    const int s = w * 8 + si;
    const int p = ow[48 + s];
    const int c1 = lane + 64;
    const float v0 = Sb[s * 129 + lane];
    const float v1 = Sb[s * 129 + c1];
    const int pi0 = t0 - 48 + lane;
    const bool valid0 = (lane >= s) && (pi0 >= 0) && (pi0 < T_DIM) && (ow[lane] <= p);
    const bool valid1 = (lane <= s + 32) && (pi0 + 64 < T_DIM) && (ow[c1] <= p);
    float mx = fmaxf(valid0 ? v0 : -FLT_MAX, valid1 ? v1 : -FLT_MAX);
#pragma unroll
    for (int off = 32; off > 0; off >>= 1) mx = fmaxf(mx, __shfl_xor(mx, off, 64));
    const float e0 = valid0 ? __expf(v0 - mx) : 0.f;
    const float e1 = valid1 ? __expf(v1 - mx) : 0.f;
    float sum = e0 + e1;
#pragma unroll
    for (int off = 32; off > 0; off >>= 1) sum += __shfl_xor(sum, off, 64);
    const float inv = 1.f / sum;
    lP[s * 136 + lane] = valid0 ? f2bf(e0 * inv) : (unsigned short)0;
    lP[s * 136 + c1]   = valid1 ? f2bf(e1 * inv) : (unsigned short)0;
  }
  __syncthreads();

  // O = P·V^T via MFMA; wave (wr,wc): m-tile wr, n-tiles wc*2+{0,1}
  {
    const int wr = w >> 1, wc = w & 1;
    f32x4 acco[2] = {};
#pragma unroll
    for (int kt = 0; kt < 4; ++kt) {
      s16x8 ap = *(const s16x8*)&lP[(wr * 16 + fm) * 136 + kt * 32 + q8];
#pragma unroll
      for (int ni = 0; ni < 2; ++ni) {
        s16x8 bv = *(const s16x8*)&lVT[((wc * 2 + ni) * 16 + fm) * 136 + kt * 32 + q8];
        acco[ni] = __builtin_amdgcn_mfma_f32_16x16x32_bf16(ap, bv, acco[ni], 0, 0, 0);
      }
    }
#pragma unroll
    for (int ni = 0; ni < 2; ++ni)
#pragma unroll
      for (int r = 0; r < 4; ++r) {
        int q = wr * 16 + q4 * 4 + r;
        int d = (wc * 2 + ni) * 16 + fm;
        Ybf[(size_t)ow[48 + q] * C_DIM + h * 64 + d] = f2bf(acco[ni][r]);
      }
  }
}

// ---------------------------------------------------------------------------
extern "C" void kernel_launch(void* const* d_in, const int* in_sizes, int n_in,
                              void* d_out, int out_size, void* d_ws, size_t ws_size,
                              hipStream_t stream) {
  const float* x     = (const float*)d_in[0];
  const float* Wqkv  = (const float*)d_in[1];
  const float* Wout  = (const float*)d_in[2];
  const int*   perms = (const int*)d_in[3];
  float* out = (float*)d_out;
  unsigned short* ws = (unsigned short*)d_ws;

  unsigned short* xbf   = ws;                    // 2048*512
  unsigned short* WqkvT = xbf + 1048576;         // [1536][512]
  unsigned short* WoutT = WqkvT + 786432;        // [512][512]
  unsigned short* qkvbf = WoutT + 262144;        // [2048][1536]
  unsigned short* Ybf   = qkvbf + 3145728;       // [2048][512]

  prep_kernel<<<NBLK, 256, 0, stream>>>(x, Wqkv, Wout, xbf, WqkvT, WoutT);
  gemm1_kernel<<<384, 256, 0, stream>>>(xbf, WqkvT, qkvbf);
  attn_kernel<<<NBLK, 256, 0, stream>>>(qkvbf, perms, Ybf);
  gemm2_kernel<<<256, 256, 0, stream>>>(Ybf, WoutT, out);
}